// Round 1
// baseline (3696.379 us; speedup 1.0000x reference)
//
#include <hip/hip_runtime.h>
#include <math.h>

// PhaseNN: phase-oscillator ODE integrator on MI355X.
// Design:
//   grid = 256 blocks = 32 row-groups (8 batch rows) x 8 N-slices (128 cols), 256 thr/block.
//   cos/sin(xi) slice tables pre-converted to bf16 MFMA A-fragments held in REGISTERS
//   (both contraction orientations, 128 VGPR/thread) -> zero table traffic in the loop.
//   Per eval: pack cos/sin(phi) -> GEMM1 (m partial, 16x16x32 bf16 MFMA, transposed
//   D[p][b]) -> global pm exchange + 8-block group barrier (atomic spin, XCD-local) ->
//   redundant reduce + softmax (in-register, half-wave shuffle) -> GEMM2 (wc/ws,
//   transposed D[c][b]) -> RK4 combine (fp32).  64 evals, 1 barrier each.
//   pm double-buffered by eval parity; counters monotonic (memset per launch).
// ws usage: 2 MiB pm + 4 KiB barrier counters.

typedef __attribute__((ext_vector_type(4))) float f32x4;
typedef __attribute__((ext_vector_type(8))) short bf16x8;
typedef __attribute__((ext_vector_type(4))) unsigned short u16x4;

struct TCons { float s[64]; float c[64]; };

__device__ __forceinline__ unsigned short f2bf(float f) {
  unsigned u = __builtin_bit_cast(unsigned, f);
  return (unsigned short)((u + 0x7FFFu + ((u >> 16) & 1u)) >> 16);
}

__global__ __launch_bounds__(256, 1) void phasenn_kernel(
    const float* __restrict__ x, const float* __restrict__ W_enc,
    const float* __restrict__ b_enc, const float* __restrict__ xi,
    const float* __restrict__ W_out, const float* __restrict__ b_out,
    float* __restrict__ dout, float* __restrict__ pm,
    unsigned int* __restrict__ bar, TCons tc)
{
  // LDS: 58112 B total (<64 KiB static limit)
  __shared__ __align__(16) char  A1c[8448];   // A1 (16x256 bf16, swizzled) / coup (2x8x132 f32) overlay
  __shared__ __align__(16) char  wtc[4096];   // w  (16x128 bf16, swizzled; pad rows zero)
  __shared__ __align__(16) float csf[2048];   // [0..1023]=cos(pw), [1024..2047]=sin(pw), fp32
  __shared__ __align__(16) float phi0s[1024]; // 8 rows x 128 cols
  __shared__ __align__(16) float kaccs[1024];
  __shared__ __align__(16) float pws[1024];
  __shared__ __align__(16) float xst[8*784];  // staged x rows (encoder only)

  const int tid  = threadIdx.x;
  const int g    = blockIdx.x & 31;   // row-group: blocks {g, g+32,...} share XCD (bid%8==g%8)
  const int j    = blockIdx.x >> 5;   // N-slice
  const int jn0  = j << 7;
  const int wave = tid >> 6;
  const int lane = tid & 63;
  const int b16  = lane & 15;
  const int q    = lane >> 4;

  // ---- prologue: zero w-table (pad rows b>=8 must stay 0)
  for (int idx = tid; idx < 2048; idx += 256) ((unsigned short*)wtc)[idx] = 0;

  // ---- prologue: stage x rows into LDS
  for (int idx = tid; idx < 8*784; idx += 256) {
    int bb = idx / 784;
    xst[idx] = x[(g*8 + bb)*784 + (idx - bb*784)];
  }
  __syncthreads();

  // ---- prologue: encoder  phi0 = 2pi*sigmoid(x @ W_enc^T + b_enc)  (fp32 VALU)
  {
    const int b = tid >> 5, nl = (tid & 31) << 2;
    #pragma unroll
    for (int u = 0; u < 4; ++u) {
      const int ng = jn0 + nl + u;
      const float* wr = W_enc + ng*784;
      const float* xr = xst + b*784;
      float acc = b_enc[ng];
      #pragma unroll 4
      for (int d = 0; d < 784; d += 4) {
        f32x4 wv = *(const f32x4*)(wr + d);
        f32x4 xv = *(const f32x4*)(xr + d);
        acc += wv[0]*xv[0] + wv[1]*xv[1] + wv[2]*xv[2] + wv[3]*xv[3];
      }
      float ph = 6.283185307179586f / (1.0f + __expf(-acc));
      phi0s[b*128 + nl + u] = ph;
      pws  [b*128 + nl + u] = ph;
    }
  }

  // ---- prologue: build table fragments in registers (bf16)
  // GEMM1 (transposed): D[p][b] = sum_k T1[p][k] * A1[k][b];  A-frag: lane holds
  // T1[p = pt*16 + b16][k = kk*32 + q*8 + i];  k<128 -> cos(xi[p][n]), else sin.
  bf16x8 t1f[2][8];
  #pragma unroll
  for (int tt = 0; tt < 2; ++tt) {
    const int p = (wave*2 + tt)*16 + b16;
    #pragma unroll
    for (int kk = 0; kk < 8; ++kk) {
      const int base = (kk & 3)*32 + q*8;
      const float* src = xi + p*1024 + jn0 + base;
      f32x4 v0 = *(const f32x4*)(src);
      f32x4 v1 = *(const f32x4*)(src + 4);
      bf16x8 fr;
      #pragma unroll
      for (int i = 0; i < 8; ++i) {
        float xv = (i < 4) ? v0[i] : v1[i-4];
        float t  = (kk < 4) ? cosf(xv) : sinf(xv);
        fr[i] = (short)f2bf(t);
      }
      t1f[tt][kk] = fr;
    }
  }
  // GEMM2 (transposed): D[c][b] = sum_p T2[c][p] * w[p][b];  A-frag: lane holds
  // T2[c = ct*16 + b16][p = kk*32 + q*8 + i]; c<128 -> cos(xi[p][jn0+c]), else sin.
  bf16x8 t2f[4][4];
  #pragma unroll
  for (int u = 0; u < 4; ++u) {
    const int c   = (wave + 4*u)*16 + b16;
    const int col = jn0 + (c & 127);
    const bool isc = (c < 128);
    #pragma unroll
    for (int kk = 0; kk < 4; ++kk) {
      bf16x8 fr;
      #pragma unroll
      for (int i = 0; i < 8; ++i) {
        const int p = kk*32 + q*8 + i;
        float xv = xi[p*1024 + col];
        fr[i] = (short)f2bf(isc ? cosf(xv) : sinf(xv));
      }
      t2f[u][kk] = fr;
    }
  }
  __syncthreads();

  const float dtf = 0.03125f, half = 0.015625f;
  const float sixth = (float)(0.03125/6.0);

  for (int e = 0; e < 64; ++e) {
    // ---- Phase A: cos/sin(pw) -> csf (fp32) + A1 (bf16 swizzled, rows 0..7)
    {
      const int b = tid >> 5, nb = (tid & 31) << 2;
      f32x4 pv = *(const f32x4*)(pws + b*128 + nb);
      f32x4 cv, sv; u16x4 ch, sh;
      #pragma unroll
      for (int u = 0; u < 4; ++u) {
        float ss, cc; sincosf(pv[u], &ss, &cc);
        cv[u] = cc; sv[u] = ss;
        ch[u] = f2bf(cc); sh[u] = f2bf(ss);
      }
      *(f32x4*)(csf + b*128 + nb)        = cv;
      *(f32x4*)(csf + 1024 + b*128 + nb) = sv;
      const int chunk = nb >> 3, lo = (nb & 7)*2;
      *(u16x4*)(A1c + b*512 + ((chunk        ^ b) << 4) + lo) = ch; // k = nb   (cos half)
      *(u16x4*)(A1c + b*512 + (((16 + chunk) ^ b) << 4) + lo) = sh; // k = nb+128 (sin half)
    }
    __syncthreads();

    // ---- Phase B: GEMM1 -> pm[e&1] (partial m over this slice)
    {
      bf16x8 bfr[8];
      #pragma unroll
      for (int kk = 0; kk < 8; ++kk)
        bfr[kk] = *(const bf16x8*)(A1c + b16*512 + (((kk*4 + q) ^ b16) << 4));
      f32x4 a0 = {0.f,0.f,0.f,0.f}, a1 = {0.f,0.f,0.f,0.f};
      #pragma unroll
      for (int kk = 0; kk < 8; ++kk) {
        a0 = __builtin_amdgcn_mfma_f32_16x16x32_bf16(t1f[0][kk], bfr[kk], a0, 0, 0, 0);
        a1 = __builtin_amdgcn_mfma_f32_16x16x32_bf16(t1f[1][kk], bfr[kk], a1, 0, 0, 0);
      }
      if (b16 < 8) { // D cols b16>=8 are padding
        float* dst = pm + (e & 1)*262144 + j*32768 + g*1024 + b16*128;
        #pragma unroll
        for (int r = 0; r < 4; ++r) {
          dst[(wave*2+0)*16 + q*4 + r] = a0[r];
          dst[(wave*2+1)*16 + q*4 + r] = a1[r];
        }
      }
    }
    __threadfence();      // drain pm stores to device scope (release)
    __syncthreads();
    if (tid == 0) {       // group barrier: 8 slice-blocks of group g
      __hip_atomic_fetch_add(bar + g*32, 1u, __ATOMIC_RELEASE, __HIP_MEMORY_SCOPE_AGENT);
      const unsigned tgt = 8u*(unsigned)(e + 1);
      while (__hip_atomic_load(bar + g*32, __ATOMIC_ACQUIRE, __HIP_MEMORY_SCOPE_AGENT) < tgt)
        __builtin_amdgcn_s_sleep(2);
    }
    __syncthreads();
    __threadfence();      // acquire: invalidate L1 before reading siblings' pm

    // ---- Phase C: reduce partials (redundantly, deterministic order) + softmax -> wt
    {
      const int b = tid >> 5, pb = (tid & 31) << 2;
      const float* src = pm + (e & 1)*262144 + g*1024 + b*128 + pb;
      f32x4 ms = {0.f,0.f,0.f,0.f};
      #pragma unroll
      for (int jj = 0; jj < 8; ++jj) ms += *(const f32x4*)(src + jj*32768);
      f32x4 ev;
      #pragma unroll
      for (int u = 0; u < 4; ++u) ev[u] = __expf(ms[u] * 0.001953125f); // BETA/N = 2/1024
      float s4 = ev[0]+ev[1]+ev[2]+ev[3];
      #pragma unroll
      for (int off = 1; off < 32; off <<= 1) s4 += __shfl_xor(s4, off, 32);
      const float inv = 1.0f / s4;
      u16x4 wv;
      #pragma unroll
      for (int u = 0; u < 4; ++u) wv[u] = f2bf(ev[u]*inv);
      const int chunk = pb >> 3;
      *(u16x4*)(wtc + b*256 + (((chunk ^ b) & 15) << 4) + (pb & 7)*2) = wv;
    }
    __syncthreads();

    // ---- Phase D: GEMM2 -> coup (overlay A1c; A1 dead after Phase B)
    {
      bf16x8 wfr[4];
      #pragma unroll
      for (int kk = 0; kk < 4; ++kk)
        wfr[kk] = *(const bf16x8*)(wtc + b16*256 + ((((kk*4 + q) ^ b16) & 15) << 4));
      f32x4 ac[4];
      #pragma unroll
      for (int u = 0; u < 4; ++u) ac[u] = (f32x4){0.f,0.f,0.f,0.f};
      #pragma unroll
      for (int kk = 0; kk < 4; ++kk) {
        #pragma unroll
        for (int u = 0; u < 4; ++u)
          ac[u] = __builtin_amdgcn_mfma_f32_16x16x32_bf16(t2f[u][kk], wfr[kk], ac[u], 0, 0, 0);
      }
      float* cp = (float*)A1c;   // coup[sc][b][n], row stride 132 (padded, bank-friendly)
      if (b16 < 8) {
        #pragma unroll
        for (int u = 0; u < 4; ++u) {
          const int c  = (wave + 4*u)*16 + q*4;
          const int sc = c >> 7, nl = c & 127;
          #pragma unroll
          for (int r = 0; r < 4; ++r)
            cp[sc*1056 + b16*132 + nl + r] = ac[u][r];
        }
      }
    }
    __syncthreads();

    // ---- Phase E: combine + RK4 update (fp32)
    {
      const int b = tid >> 5, nb = (tid & 31) << 2;
      const float* cp = (const float*)A1c;
      f32x4 wc = *(const f32x4*)(cp + b*132 + nb);
      f32x4 wsv = *(const f32x4*)(cp + 1056 + b*132 + nb);
      f32x4 cf = *(const f32x4*)(csf + b*128 + nb);
      f32x4 sf = *(const f32x4*)(csf + 1024 + b*128 + nb);
      const float swt = tc.s[e], cwt = tc.c[e];
      f32x4 kv;
      #pragma unroll
      for (int u = 0; u < 4; ++u)
        kv[u] = (sf[u]*wc[u] - cf[u]*wsv[u])              // K_COUP = 1
              + 0.08f*(swt*cf[u] - cwt*sf[u]);            // A*sin(wt - phi)
      f32x4 ph0 = *(const f32x4*)(phi0s + b*128 + nb);
      const int st = e & 3;
      f32x4 ka, pw;
      if (st == 0)      { ka = kv;                                              pw = ph0 + kv*half; }
      else if (st == 1) { ka = *(const f32x4*)(kaccs + b*128 + nb) + kv*2.0f;   pw = ph0 + kv*half; }
      else if (st == 2) { ka = *(const f32x4*)(kaccs + b*128 + nb) + kv*2.0f;   pw = ph0 + kv*dtf; }
      else {
        ka = *(const f32x4*)(kaccs + b*128 + nb) + kv;
        f32x4 pn = ph0 + ka*sixth;
        pw = pn;
        *(f32x4*)(phi0s + b*128 + nb) = pn;
      }
      *(f32x4*)(kaccs + b*128 + nb) = ka;
      *(f32x4*)(pws   + b*128 + nb) = pw;
    }
    __syncthreads();
  }

  // ---- epilogue: readout  out = [cos phiT, sin phiT] @ W_out^T + b_out
  {
    const int b = tid >> 5, nb = (tid & 31) << 2;
    f32x4 ph = *(const f32x4*)(phi0s + b*128 + nb);
    float part[10];
    #pragma unroll
    for (int cl = 0; cl < 10; ++cl) part[cl] = 0.0f;
    #pragma unroll
    for (int u = 0; u < 4; ++u) {
      float ss, cc; sincosf(ph[u], &ss, &cc);
      const int ng = jn0 + nb + u;
      #pragma unroll
      for (int cl = 0; cl < 10; ++cl)
        part[cl] += cc * W_out[cl*2048 + ng] + ss * W_out[cl*2048 + 1024 + ng];
    }
    #pragma unroll
    for (int off = 16; off >= 1; off >>= 1) {
      #pragma unroll
      for (int cl = 0; cl < 10; ++cl)
        part[cl] += __shfl_xor(part[cl], off, 32);
    }
    if ((tid & 31) == 0) {
      const int row = g*8 + b;
      #pragma unroll
      for (int cl = 0; cl < 10; ++cl) {
        float v = part[cl];
        if (j == 0) v += b_out[cl];
        atomicAdd(dout + row*10 + cl, v);
      }
    }
  }
}

extern "C" void kernel_launch(void* const* d_in, const int* in_sizes, int n_in,
                              void* d_out, int out_size, void* d_ws, size_t ws_size,
                              hipStream_t stream) {
  (void)in_sizes; (void)n_in; (void)ws_size;
  const float* x     = (const float*)d_in[0];
  const float* W_enc = (const float*)d_in[1];
  const float* b_enc = (const float*)d_in[2];
  const float* xi    = (const float*)d_in[3];
  const float* W_out = (const float*)d_in[4];
  const float* b_out = (const float*)d_in[5];
  float* out = (float*)d_out;

  float* pm = (float*)d_ws;                                   // 2 MiB, no init needed
  unsigned int* bar = (unsigned int*)((char*)d_ws + 2*1024*1024); // 4 KiB counters

  hipMemsetAsync(d_out, 0, (size_t)out_size * sizeof(float), stream);
  hipMemsetAsync(bar, 0, 4096, stream);

  TCons tc;
  const double OME = 2.0 * 3.14159265358979323846 * 200.0;
  const double dtd = 0.03125;
  const double co[4] = {0.0, 0.5, 0.5, 1.0};
  for (int e = 0; e < 64; ++e) {
    double t = ((double)(e >> 2) + co[e & 3]) * dtd;
    tc.s[e] = (float)sin(OME * t);
    tc.c[e] = (float)cos(OME * t);
  }

  phasenn_kernel<<<dim3(256), dim3(256), 0, stream>>>(
      x, W_enc, b_enc, xi, W_out, b_out, out, pm, bar, tc);
}

// Round 2
// 795.258 us; speedup vs baseline: 4.6480x; 4.6480x over previous
//
#include <hip/hip_runtime.h>
#include <math.h>

// PhaseNN: phase-oscillator ODE integrator on MI355X.
// Design:
//   grid = 256 blocks = 32 row-groups (8 batch rows) x 8 N-slices (128 cols), 256 thr/block.
//   cos/sin(xi) slice tables pre-converted to bf16 MFMA A-fragments held in REGISTERS
//   (both contraction orientations) -> zero table traffic in the loop.
//   Per eval: pack cos/sin(phi) -> GEMM1 (m partial, 16x16x32 bf16 MFMA, transposed
//   D[p][b]) -> pm exchange via RELAXED agent-scope atomics (sc-bit coherent at IF$,
//   NO buffer_inv/wbl2 — ordered fences cost a full L2 writeback on gfx950!) ->
//   per-block flag barrier (8-lane parallel poll) -> redundant reduce + softmax ->
//   GEMM2 (wc/ws, transposed D[c][b]) -> RK4 combine (fp32).  64 evals, 1 barrier each.
//   pm double-buffered by eval parity; flags monotonic (memset per launch).
// ws usage: 2 MiB pm + 16 KiB flags.

typedef __attribute__((ext_vector_type(4))) float f32x4;
typedef __attribute__((ext_vector_type(8))) short bf16x8;
typedef __attribute__((ext_vector_type(4))) unsigned short u16x4;

struct TCons { float s[64]; float c[64]; };

__device__ __forceinline__ unsigned short f2bf(float f) {
  unsigned u = __builtin_bit_cast(unsigned, f);
  return (unsigned short)((u + 0x7FFFu + ((u >> 16) & 1u)) >> 16);
}

__global__ __launch_bounds__(256, 1) void phasenn_kernel(
    const float* __restrict__ x, const float* __restrict__ W_enc,
    const float* __restrict__ b_enc, const float* __restrict__ xi,
    const float* __restrict__ W_out, const float* __restrict__ b_out,
    float* __restrict__ dout, float* __restrict__ pm,
    unsigned int* __restrict__ flags, TCons tc)
{
  // LDS: 58112 B total (<64 KiB static limit)
  __shared__ __align__(16) char  A1c[8448];   // A1 (16x256 bf16, swizzled) / coup (2x8x132 f32) overlay
  __shared__ __align__(16) char  wtc[4096];   // w  (16x128 bf16, swizzled; pad rows zero)
  __shared__ __align__(16) float csf[2048];   // [0..1023]=cos(pw), [1024..2047]=sin(pw), fp32
  __shared__ __align__(16) float phi0s[1024]; // 8 rows x 128 cols
  __shared__ __align__(16) float kaccs[1024];
  __shared__ __align__(16) float pws[1024];
  __shared__ __align__(16) float xst[8*784];  // staged x rows (encoder only)

  const int tid  = threadIdx.x;
  const int g    = blockIdx.x & 31;   // row-group
  const int j    = blockIdx.x >> 5;   // N-slice
  const int jn0  = j << 7;
  const int wave = tid >> 6;
  const int lane = tid & 63;
  const int b16  = lane & 15;
  const int q    = lane >> 4;

  // ---- prologue: zero w-table (pad rows b>=8 must stay 0)
  for (int idx = tid; idx < 2048; idx += 256) ((unsigned short*)wtc)[idx] = 0;

  // ---- prologue: stage x rows into LDS
  for (int idx = tid; idx < 8*784; idx += 256) {
    int bb = idx / 784;
    xst[idx] = x[(g*8 + bb)*784 + (idx - bb*784)];
  }
  __syncthreads();

  // ---- prologue: encoder  phi0 = 2pi*sigmoid(x @ W_enc^T + b_enc)  (fp32 VALU)
  {
    const int b = tid >> 5, nl = (tid & 31) << 2;
    #pragma unroll
    for (int u = 0; u < 4; ++u) {
      const int ng = jn0 + nl + u;
      const float* wr = W_enc + ng*784;
      const float* xr = xst + b*784;
      float acc = b_enc[ng];
      #pragma unroll 4
      for (int d = 0; d < 784; d += 4) {
        f32x4 wv = *(const f32x4*)(wr + d);
        f32x4 xv = *(const f32x4*)(xr + d);
        acc += wv[0]*xv[0] + wv[1]*xv[1] + wv[2]*xv[2] + wv[3]*xv[3];
      }
      float ph = 6.283185307179586f / (1.0f + __expf(-acc));
      phi0s[b*128 + nl + u] = ph;
      pws  [b*128 + nl + u] = ph;
    }
  }

  // ---- prologue: build table fragments in registers (bf16)
  // GEMM1 (transposed): D[p][b] = sum_k T1[p][k] * A1[k][b];  A-frag: lane holds
  // T1[p = pt*16 + b16][k = kk*32 + q*8 + i];  k<128 -> cos(xi[p][n]), else sin.
  bf16x8 t1f[2][8];
  #pragma unroll
  for (int tt = 0; tt < 2; ++tt) {
    const int p = (wave*2 + tt)*16 + b16;
    #pragma unroll
    for (int kk = 0; kk < 8; ++kk) {
      const int base = (kk & 3)*32 + q*8;
      const float* src = xi + p*1024 + jn0 + base;
      f32x4 v0 = *(const f32x4*)(src);
      f32x4 v1 = *(const f32x4*)(src + 4);
      bf16x8 fr;
      #pragma unroll
      for (int i = 0; i < 8; ++i) {
        float xv = (i < 4) ? v0[i] : v1[i-4];
        float t  = (kk < 4) ? cosf(xv) : sinf(xv);
        fr[i] = (short)f2bf(t);
      }
      t1f[tt][kk] = fr;
    }
  }
  // GEMM2 (transposed): D[c][b] = sum_p T2[c][p] * w[p][b];  A-frag: lane holds
  // T2[c = ct*16 + b16][p = kk*32 + q*8 + i]; c<128 -> cos(xi[p][jn0+c]), else sin.
  bf16x8 t2f[4][4];
  #pragma unroll
  for (int u = 0; u < 4; ++u) {
    const int c   = (wave + 4*u)*16 + b16;
    const int col = jn0 + (c & 127);
    const bool isc = (c < 128);
    #pragma unroll
    for (int kk = 0; kk < 4; ++kk) {
      bf16x8 fr;
      #pragma unroll
      for (int i = 0; i < 8; ++i) {
        const int p = kk*32 + q*8 + i;
        float xv = xi[p*1024 + col];
        fr[i] = (short)f2bf(isc ? cosf(xv) : sinf(xv));
      }
      t2f[u][kk] = fr;
    }
  }
  __syncthreads();

  const float dtf = 0.03125f, half = 0.015625f;
  const float sixth = (float)(0.03125/6.0);

  for (int e = 0; e < 64; ++e) {
    // ---- Phase A: cos/sin(pw) -> csf (fp32) + A1 (bf16 swizzled, rows 0..7)
    {
      const int b = tid >> 5, nb = (tid & 31) << 2;
      f32x4 pv = *(const f32x4*)(pws + b*128 + nb);
      f32x4 cv, sv; u16x4 ch, sh;
      #pragma unroll
      for (int u = 0; u < 4; ++u) {
        float ss, cc; sincosf(pv[u], &ss, &cc);
        cv[u] = cc; sv[u] = ss;
        ch[u] = f2bf(cc); sh[u] = f2bf(ss);
      }
      *(f32x4*)(csf + b*128 + nb)        = cv;
      *(f32x4*)(csf + 1024 + b*128 + nb) = sv;
      const int chunk = nb >> 3, lo = (nb & 7)*2;
      *(u16x4*)(A1c + b*512 + ((chunk        ^ b) << 4) + lo) = ch; // k = nb   (cos half)
      *(u16x4*)(A1c + b*512 + (((16 + chunk) ^ b) << 4) + lo) = sh; // k = nb+128 (sin half)
    }
    __syncthreads();

    // ---- Phase B: GEMM1 -> pm[e&1] (partial m over this slice), relaxed agent atomics
    {
      bf16x8 bfr[8];
      #pragma unroll
      for (int kk = 0; kk < 8; ++kk)
        bfr[kk] = *(const bf16x8*)(A1c + b16*512 + (((kk*4 + q) ^ b16) << 4));
      f32x4 a0 = {0.f,0.f,0.f,0.f}, a1 = {0.f,0.f,0.f,0.f};
      #pragma unroll
      for (int kk = 0; kk < 8; ++kk) {
        a0 = __builtin_amdgcn_mfma_f32_16x16x32_bf16(t1f[0][kk], bfr[kk], a0, 0, 0, 0);
        a1 = __builtin_amdgcn_mfma_f32_16x16x32_bf16(t1f[1][kk], bfr[kk], a1, 0, 0, 0);
      }
      if (b16 < 8) { // D cols b16>=8 are padding
        float* dst = pm + (e & 1)*262144 + j*32768 + g*1024 + b16*128;
        #pragma unroll
        for (int r = 0; r < 4; ++r) {
          __hip_atomic_store(dst + (wave*2+0)*16 + q*4 + r, a0[r],
                             __ATOMIC_RELAXED, __HIP_MEMORY_SCOPE_AGENT);
          __hip_atomic_store(dst + (wave*2+1)*16 + q*4 + r, a1[r],
                             __ATOMIC_RELAXED, __HIP_MEMORY_SCOPE_AGENT);
        }
      }
    }
    __syncthreads();   // drains vmcnt(0): pm stores are at the coherence point
    if (tid == 0)      // publish: this block finished eval e
      __hip_atomic_store(flags + (g*8 + j)*16, (unsigned)(e + 1),
                         __ATOMIC_RELAXED, __HIP_MEMORY_SCOPE_AGENT);
    if (wave == 0 && lane < 8) {  // 8-lane parallel poll of the group's 8 flags
      while (__hip_atomic_load(flags + (g*8 + lane)*16,
                               __ATOMIC_RELAXED, __HIP_MEMORY_SCOPE_AGENT)
             < (unsigned)(e + 1))
        __builtin_amdgcn_s_sleep(1);
    }
    __syncthreads();

    // ---- Phase C: reduce partials (redundantly, deterministic order) + softmax -> wt
    {
      const int b = tid >> 5, pb = (tid & 31) << 2;
      const float* src = pm + (e & 1)*262144 + g*1024 + b*128 + pb;
      f32x4 ms = {0.f,0.f,0.f,0.f};
      #pragma unroll
      for (int jj = 0; jj < 8; ++jj) {
        #pragma unroll
        for (int u = 0; u < 4; ++u)
          ms[u] += __hip_atomic_load(src + jj*32768 + u,
                                     __ATOMIC_RELAXED, __HIP_MEMORY_SCOPE_AGENT);
      }
      f32x4 ev;
      #pragma unroll
      for (int u = 0; u < 4; ++u) ev[u] = __expf(ms[u] * 0.001953125f); // BETA/N = 2/1024
      float s4 = ev[0]+ev[1]+ev[2]+ev[3];
      #pragma unroll
      for (int off = 1; off < 32; off <<= 1) s4 += __shfl_xor(s4, off, 32);
      const float inv = 1.0f / s4;
      u16x4 wv;
      #pragma unroll
      for (int u = 0; u < 4; ++u) wv[u] = f2bf(ev[u]*inv);
      const int chunk = pb >> 3;
      *(u16x4*)(wtc + b*256 + (((chunk ^ b) & 15) << 4) + (pb & 7)*2) = wv;
    }
    __syncthreads();

    // ---- Phase D: GEMM2 -> coup (overlay A1c; A1 dead after Phase B)
    {
      bf16x8 wfr[4];
      #pragma unroll
      for (int kk = 0; kk < 4; ++kk)
        wfr[kk] = *(const bf16x8*)(wtc + b16*256 + ((((kk*4 + q) ^ b16) & 15) << 4));
      f32x4 ac[4];
      #pragma unroll
      for (int u = 0; u < 4; ++u) ac[u] = (f32x4){0.f,0.f,0.f,0.f};
      #pragma unroll
      for (int kk = 0; kk < 4; ++kk) {
        #pragma unroll
        for (int u = 0; u < 4; ++u)
          ac[u] = __builtin_amdgcn_mfma_f32_16x16x32_bf16(t2f[u][kk], wfr[kk], ac[u], 0, 0, 0);
      }
      float* cp = (float*)A1c;   // coup[sc][b][n], row stride 132 (padded, bank-friendly)
      if (b16 < 8) {
        #pragma unroll
        for (int u = 0; u < 4; ++u) {
          const int c  = (wave + 4*u)*16 + q*4;
          const int sc = c >> 7, nl = c & 127;
          #pragma unroll
          for (int r = 0; r < 4; ++r)
            cp[sc*1056 + b16*132 + nl + r] = ac[u][r];
        }
      }
    }
    __syncthreads();

    // ---- Phase E: combine + RK4 update (fp32)
    {
      const int b = tid >> 5, nb = (tid & 31) << 2;
      const float* cp = (const float*)A1c;
      f32x4 wc = *(const f32x4*)(cp + b*132 + nb);
      f32x4 wsv = *(const f32x4*)(cp + 1056 + b*132 + nb);
      f32x4 cf = *(const f32x4*)(csf + b*128 + nb);
      f32x4 sf = *(const f32x4*)(csf + 1024 + b*128 + nb);
      const float swt = tc.s[e], cwt = tc.c[e];
      f32x4 kv;
      #pragma unroll
      for (int u = 0; u < 4; ++u)
        kv[u] = (sf[u]*wc[u] - cf[u]*wsv[u])              // K_COUP = 1
              + 0.08f*(swt*cf[u] - cwt*sf[u]);            // A*sin(wt - phi)
      f32x4 ph0 = *(const f32x4*)(phi0s + b*128 + nb);
      const int st = e & 3;
      f32x4 ka, pw;
      if (st == 0)      { ka = kv;                                              pw = ph0 + kv*half; }
      else if (st == 1) { ka = *(const f32x4*)(kaccs + b*128 + nb) + kv*2.0f;   pw = ph0 + kv*half; }
      else if (st == 2) { ka = *(const f32x4*)(kaccs + b*128 + nb) + kv*2.0f;   pw = ph0 + kv*dtf; }
      else {
        ka = *(const f32x4*)(kaccs + b*128 + nb) + kv;
        f32x4 pn = ph0 + ka*sixth;
        pw = pn;
        *(f32x4*)(phi0s + b*128 + nb) = pn;
      }
      *(f32x4*)(kaccs + b*128 + nb) = ka;
      *(f32x4*)(pws   + b*128 + nb) = pw;
    }
    __syncthreads();
  }

  // ---- epilogue: readout  out = [cos phiT, sin phiT] @ W_out^T + b_out
  {
    const int b = tid >> 5, nb = (tid & 31) << 2;
    f32x4 ph = *(const f32x4*)(phi0s + b*128 + nb);
    float part[10];
    #pragma unroll
    for (int cl = 0; cl < 10; ++cl) part[cl] = 0.0f;
    #pragma unroll
    for (int u = 0; u < 4; ++u) {
      float ss, cc; sincosf(ph[u], &ss, &cc);
      const int ng = jn0 + nb + u;
      #pragma unroll
      for (int cl = 0; cl < 10; ++cl)
        part[cl] += cc * W_out[cl*2048 + ng] + ss * W_out[cl*2048 + 1024 + ng];
    }
    #pragma unroll
    for (int off = 16; off >= 1; off >>= 1) {
      #pragma unroll
      for (int cl = 0; cl < 10; ++cl)
        part[cl] += __shfl_xor(part[cl], off, 32);
    }
    if ((tid & 31) == 0) {
      const int row = g*8 + b;
      #pragma unroll
      for (int cl = 0; cl < 10; ++cl) {
        float v = part[cl];
        if (j == 0) v += b_out[cl];
        atomicAdd(dout + row*10 + cl, v);
      }
    }
  }
}

extern "C" void kernel_launch(void* const* d_in, const int* in_sizes, int n_in,
                              void* d_out, int out_size, void* d_ws, size_t ws_size,
                              hipStream_t stream) {
  (void)in_sizes; (void)n_in; (void)ws_size;
  const float* x     = (const float*)d_in[0];
  const float* W_enc = (const float*)d_in[1];
  const float* b_enc = (const float*)d_in[2];
  const float* xi    = (const float*)d_in[3];
  const float* W_out = (const float*)d_in[4];
  const float* b_out = (const float*)d_in[5];
  float* out = (float*)d_out;

  float* pm = (float*)d_ws;                                       // 2 MiB
  unsigned int* flags = (unsigned int*)((char*)d_ws + 2*1024*1024); // 16 KiB flag slots

  hipMemsetAsync(d_out, 0, (size_t)out_size * sizeof(float), stream);
  hipMemsetAsync(flags, 0, 16384, stream);

  TCons tc;
  const double OME = 2.0 * 3.14159265358979323846 * 200.0;
  const double dtd = 0.03125;
  const double co[4] = {0.0, 0.5, 0.5, 1.0};
  for (int e = 0; e < 64; ++e) {
    double t = ((double)(e >> 2) + co[e & 3]) * dtd;
    tc.s[e] = (float)sin(OME * t);
    tc.c[e] = (float)cos(OME * t);
  }

  phasenn_kernel<<<dim3(256), dim3(256), 0, stream>>>(
      x, W_enc, b_enc, xi, W_out, b_out, out, pm, flags, tc);
}

// Round 5
// 769.431 us; speedup vs baseline: 4.8040x; 1.0336x over previous
//
#include <hip/hip_runtime.h>
#include <math.h>

// PhaseNN: phase-oscillator ODE integrator on MI355X.
// Design:
//   grid = 256 blocks = 32 row-groups (8 batch rows) x 8 N-slices (128 cols), 256 thr/block.
//   cos/sin(xi) slice tables pre-converted to bf16 MFMA A-fragments held in REGISTERS.
//   Per eval: pack cos/sin(phi) -> GEMM1 (m partial, 16x16x32 bf16 MFMA) ->
//   TWO-PHASE EXCHANGE (all relaxed agent-scope atomics, the Round-2-proven primitive;
//   no fences -> no L2 writeback/invalidate):
//     B:  publish bf16 m-partial (2 KB/block, packed 64-bit atomic stores), flagA barrier
//     C1: block j stripe-reduces patterns [16j,16j+16) (reads 8x512 B), exp,
//         stripe denom via shfl, publishes unnorm-w bf16 + stripe sum, flagB barrier
//     C2: read full unnorm-w (2 KB) + 8 stripe sums, normalize locally -> GEMM2 -> RK4.
//   vs Round 2 (every block redundantly reads 8x4 KB fp32 = 8 MB/eval at IF$): traffic
//   drops ~5x to ~1.6 MB/eval; 2 barriers/eval instead of 1 (latency ~2.5 us, BW ~1.4 us).
//   Rounds 3/4 (inline-asm sc0 L2 exchange + XCC discovery) hung opaquely twice -> reverted;
//   this build uses ONLY mechanisms that passed in Round 2.
// ws: [0,1 MiB) bf16 m-partials (2 parity x 256 slots x 2 KB);
//     [1 MiB,1.25 MiB) w-exchange (2 parity x 256 slots x 512 B: 256 B w + 32 B denom);
//     [2 MiB, 2 MiB+16 KiB) flags (256 slots x 64 B: word0=flagA, word4=flagB).

typedef __attribute__((ext_vector_type(4))) float f32x4;
typedef __attribute__((ext_vector_type(8))) short bf16x8;
typedef __attribute__((ext_vector_type(4))) unsigned short u16x4;

struct TCons { float s[64]; float c[64]; };

__device__ __forceinline__ unsigned short f2bf(float f) {
  unsigned u = __builtin_bit_cast(unsigned, f);
  return (unsigned short)((u + 0x7FFFu + ((u >> 16) & 1u)) >> 16);
}
__device__ __forceinline__ float ubf(unsigned short u) {
  unsigned x = ((unsigned)u) << 16;
  return __builtin_bit_cast(float, x);
}
__device__ __forceinline__ unsigned long long pack4bf(float a, float b, float c, float d) {
  return (unsigned long long)f2bf(a)
       | ((unsigned long long)f2bf(b) << 16)
       | ((unsigned long long)f2bf(c) << 32)
       | ((unsigned long long)f2bf(d) << 48);
}

__global__ __launch_bounds__(256, 1) void phasenn_kernel(
    const float* __restrict__ x, const float* __restrict__ W_enc,
    const float* __restrict__ b_enc, const float* __restrict__ xi,
    const float* __restrict__ W_out, const float* __restrict__ b_out,
    float* __restrict__ dout, char* __restrict__ wsb,
    unsigned int* __restrict__ ctrl, TCons tc)
{
  __shared__ __align__(16) char  A1c[8448];   // A1 (16x256 bf16, swizzled) / coup (2x8x132 f32) overlay
  __shared__ __align__(16) char  wtc[4096];   // w  (16x128 bf16, swizzled; pad rows zero)
  __shared__ __align__(16) float csf[2048];   // [0..1023]=cos(pw), [1024..2047]=sin(pw), fp32
  __shared__ __align__(16) float phi0s[1024]; // 8 rows x 128 cols
  __shared__ __align__(16) float kaccs[1024];
  __shared__ __align__(16) float pws[1024];
  __shared__ __align__(16) float xst[8*784];  // staged x rows (encoder only)
  __shared__ float invs[8];                   // per-row 1/softmax-denominator

  const int tid  = threadIdx.x;
  const int g    = blockIdx.x & 31;   // row-group
  const int j    = blockIdx.x >> 5;   // N-slice (also: owns P-stripe [16j,16j+16))
  const int jn0  = j << 7;
  const int wave = tid >> 6;
  const int lane = tid & 63;
  const int b16  = lane & 15;
  const int q    = lane >> 4;
  const int slot = g*8 + j;

  char* mpart = wsb;                  // 2 parity x 256 slots x 2048 B
  char* wub   = wsb + (1 << 20);      // 2 parity x 256 slots x 512 B

  // ---- prologue: zero w-table (pad rows b>=8 must stay 0)
  for (int idx = tid; idx < 2048; idx += 256) ((unsigned short*)wtc)[idx] = 0;

  // ---- prologue: stage x rows into LDS
  for (int idx = tid; idx < 8*784; idx += 256) {
    int bb = idx / 784;
    xst[idx] = x[(g*8 + bb)*784 + (idx - bb*784)];
  }
  __syncthreads();

  // ---- prologue: encoder  phi0 = 2pi*sigmoid(x @ W_enc^T + b_enc)  (fp32 VALU)
  {
    const int b = tid >> 5, nl = (tid & 31) << 2;
    #pragma unroll
    for (int u = 0; u < 4; ++u) {
      const int ng = jn0 + nl + u;
      const float* wr = W_enc + ng*784;
      const float* xr = xst + b*784;
      float acc = b_enc[ng];
      #pragma unroll 4
      for (int d = 0; d < 784; d += 4) {
        f32x4 wv = *(const f32x4*)(wr + d);
        f32x4 xv = *(const f32x4*)(xr + d);
        acc += wv[0]*xv[0] + wv[1]*xv[1] + wv[2]*xv[2] + wv[3]*xv[3];
      }
      float ph = 6.283185307179586f / (1.0f + __expf(-acc));
      phi0s[b*128 + nl + u] = ph;
      pws  [b*128 + nl + u] = ph;
    }
  }

  // ---- prologue: build table fragments in registers (bf16)
  // GEMM1 (transposed): D[p][b] = sum_k T1[p][k] * A1[k][b]
  bf16x8 t1f[2][8];
  #pragma unroll
  for (int tt = 0; tt < 2; ++tt) {
    const int p = (wave*2 + tt)*16 + b16;
    #pragma unroll
    for (int kk = 0; kk < 8; ++kk) {
      const int base = (kk & 3)*32 + q*8;
      const float* src = xi + p*1024 + jn0 + base;
      f32x4 v0 = *(const f32x4*)(src);
      f32x4 v1 = *(const f32x4*)(src + 4);
      bf16x8 fr;
      #pragma unroll
      for (int i = 0; i < 8; ++i) {
        float xv = (i < 4) ? v0[i] : v1[i-4];
        float t  = (kk < 4) ? cosf(xv) : sinf(xv);
        fr[i] = (short)f2bf(t);
      }
      t1f[tt][kk] = fr;
    }
  }
  // GEMM2 (transposed): D[c][b] = sum_p T2[c][p] * w[p][b]
  bf16x8 t2f[4][4];
  #pragma unroll
  for (int u = 0; u < 4; ++u) {
    const int c   = (wave + 4*u)*16 + b16;
    const int col = jn0 + (c & 127);
    const bool isc = (c < 128);
    #pragma unroll
    for (int kk = 0; kk < 4; ++kk) {
      bf16x8 fr;
      #pragma unroll
      for (int i = 0; i < 8; ++i) {
        const int p = kk*32 + q*8 + i;
        float xv = xi[p*1024 + col];
        fr[i] = (short)f2bf(isc ? cosf(xv) : sinf(xv));
      }
      t2f[u][kk] = fr;
    }
  }
  __syncthreads();

  const float dtf = 0.03125f, half = 0.015625f;
  const float sixth = (float)(0.03125/6.0);

  for (int e = 0; e < 64; ++e) {
    const int par = e & 1;
    char* mp = mpart + par*(512*1024);
    char* wb = wub   + par*(128*1024);

    // ---- Phase A: cos/sin(pw) -> csf (fp32) + A1 (bf16 swizzled, rows 0..7)
    {
      const int b = tid >> 5, nb = (tid & 31) << 2;
      f32x4 pv = *(const f32x4*)(pws + b*128 + nb);
      f32x4 cv, sv; u16x4 ch, sh;
      #pragma unroll
      for (int u = 0; u < 4; ++u) {
        float ss, cc; sincosf(pv[u], &ss, &cc);
        cv[u] = cc; sv[u] = ss;
        ch[u] = f2bf(cc); sh[u] = f2bf(ss);
      }
      *(f32x4*)(csf + b*128 + nb)        = cv;
      *(f32x4*)(csf + 1024 + b*128 + nb) = sv;
      const int chunk = nb >> 3, lo = (nb & 7)*2;
      *(u16x4*)(A1c + b*512 + ((chunk        ^ b) << 4) + lo) = ch; // k = nb   (cos half)
      *(u16x4*)(A1c + b*512 + (((16 + chunk) ^ b) << 4) + lo) = sh; // k = nb+128 (sin half)
    }
    __syncthreads();

    // ---- Phase B: GEMM1 -> bf16 m-partial publish (relaxed agent, packed 64-bit)
    {
      bf16x8 bfr[8];
      #pragma unroll
      for (int kk = 0; kk < 8; ++kk)
        bfr[kk] = *(const bf16x8*)(A1c + b16*512 + (((kk*4 + q) ^ b16) << 4));
      f32x4 a0 = {0.f,0.f,0.f,0.f}, a1 = {0.f,0.f,0.f,0.f};
      #pragma unroll
      for (int kk = 0; kk < 8; ++kk) {
        a0 = __builtin_amdgcn_mfma_f32_16x16x32_bf16(t1f[0][kk], bfr[kk], a0, 0, 0, 0);
        a1 = __builtin_amdgcn_mfma_f32_16x16x32_bf16(t1f[1][kk], bfr[kk], a1, 0, 0, 0);
      }
      if (b16 < 8) { // D cols b16>=8 are padding. Partial layout: [b (8)][P (128)] bf16.
        char* base = mp + slot*2048 + (b16*128)*2;
        unsigned long long* d0 = (unsigned long long*)(base + ((wave*2+0)*16 + q*4)*2);
        unsigned long long* d1 = (unsigned long long*)(base + ((wave*2+1)*16 + q*4)*2);
        __hip_atomic_store(d0, pack4bf(a0[0],a0[1],a0[2],a0[3]),
                           __ATOMIC_RELAXED, __HIP_MEMORY_SCOPE_AGENT);
        __hip_atomic_store(d1, pack4bf(a1[0],a1[1],a1[2],a1[3]),
                           __ATOMIC_RELAXED, __HIP_MEMORY_SCOPE_AGENT);
      }
    }
    __syncthreads();   // drains vmcnt(0): partial stores at the coherence point
    if (tid == 0)      // flagA: this block's partial for eval e is visible
      __hip_atomic_store(ctrl + slot*16, (unsigned)(e + 1),
                         __ATOMIC_RELAXED, __HIP_MEMORY_SCOPE_AGENT);
    if (tid < 8) {
      while (__hip_atomic_load(ctrl + (g*8 + tid)*16,
                               __ATOMIC_RELAXED, __HIP_MEMORY_SCOPE_AGENT)
             < (unsigned)(e + 1))
        __builtin_amdgcn_s_sleep(1);
    }
    __syncthreads();

    // ---- Phase C1: stripe-reduce patterns [16j,16j+16) over 8 partials; exp;
    //      stripe denom; publish unnorm-w bf16 + stripe sum. (32 lanes of wave 0)
    if (tid < 32) {
      const int b = tid >> 2, ck = tid & 3;
      float m0 = 0.f, m1 = 0.f, m2 = 0.f, m3 = 0.f;
      #pragma unroll
      for (int jj = 0; jj < 8; ++jj) {
        const unsigned long long* sp = (const unsigned long long*)
            (mp + (g*8 + jj)*2048 + (b*128 + j*16 + ck*4)*2);
        unsigned long long v = __hip_atomic_load(sp, __ATOMIC_RELAXED,
                                                 __HIP_MEMORY_SCOPE_AGENT);
        m0 += ubf((unsigned short)v);
        m1 += ubf((unsigned short)(v >> 16));
        m2 += ubf((unsigned short)(v >> 32));
        m3 += ubf((unsigned short)(v >> 48));
      }
      const float sc = 0.001953125f; // BETA/N = 2/1024
      float e0 = __expf(m0*sc), e1 = __expf(m1*sc), e2 = __expf(m2*sc), e3 = __expf(m3*sc);
      float s = e0 + e1 + e2 + e3;
      s += __shfl_xor(s, 1, 64);
      s += __shfl_xor(s, 2, 64);   // stripe sum for row b (lanes b*4..b*4+3 agree)
      char* wrow = wb + slot*512;
      __hip_atomic_store((unsigned long long*)(wrow + (b*16 + ck*4)*2),
                         pack4bf(e0, e1, e2, e3),
                         __ATOMIC_RELAXED, __HIP_MEMORY_SCOPE_AGENT);
      if (ck == 0)
        __hip_atomic_store((float*)(wrow + 256 + b*4), s,
                           __ATOMIC_RELAXED, __HIP_MEMORY_SCOPE_AGENT);
    }
    __syncthreads();   // wave 0's publishes drained
    if (tid == 0)      // flagB: this block's w-stripe for eval e is visible
      __hip_atomic_store(ctrl + slot*16 + 4, (unsigned)(e + 1),
                         __ATOMIC_RELAXED, __HIP_MEMORY_SCOPE_AGENT);
    if (tid < 8) {
      while (__hip_atomic_load(ctrl + (g*8 + tid)*16 + 4,
                               __ATOMIC_RELAXED, __HIP_MEMORY_SCOPE_AGENT)
             < (unsigned)(e + 1))
        __builtin_amdgcn_s_sleep(1);
    }
    __syncthreads();

    // ---- Phase C2: read full unnorm-w + stripe sums, normalize -> wtc (LDS)
    {
      const int b = tid >> 5, pb = (tid & 31) << 2;
      const int jj = pb >> 4, pi = pb & 15;
      unsigned long long wl = __hip_atomic_load(
          (const unsigned long long*)(wb + (g*8 + jj)*512 + (b*16 + pi)*2),
          __ATOMIC_RELAXED, __HIP_MEMORY_SCOPE_AGENT);
      if (tid < 64) {   // wave 0: gather 8x8 stripe sums -> invs[b]
        const int jd = tid & 7, bd = tid >> 3;
        float dv = __hip_atomic_load((const float*)(wb + (g*8 + jd)*512 + 256 + bd*4),
                                     __ATOMIC_RELAXED, __HIP_MEMORY_SCOPE_AGENT);
        dv += __shfl_xor(dv, 1, 64);
        dv += __shfl_xor(dv, 2, 64);
        dv += __shfl_xor(dv, 4, 64);
        if (jd == 0) invs[bd] = 1.0f / dv;
      }
      __syncthreads();
      const float inv = invs[b];
      u16x4 wq;
      wq[0] = f2bf(ubf((unsigned short)(wl      )) * inv);
      wq[1] = f2bf(ubf((unsigned short)(wl >> 16)) * inv);
      wq[2] = f2bf(ubf((unsigned short)(wl >> 32)) * inv);
      wq[3] = f2bf(ubf((unsigned short)(wl >> 48)) * inv);
      const int chunk = pb >> 3;
      *(u16x4*)(wtc + b*256 + (((chunk ^ b) & 15) << 4) + (pb & 7)*2) = wq;
    }
    __syncthreads();

    // ---- Phase D: GEMM2 -> coup (overlay A1c; A1 dead after Phase B)
    {
      bf16x8 wfr[4];
      #pragma unroll
      for (int kk = 0; kk < 4; ++kk)
        wfr[kk] = *(const bf16x8*)(wtc + b16*256 + ((((kk*4 + q) ^ b16) & 15) << 4));
      f32x4 ac[4];
      #pragma unroll
      for (int u = 0; u < 4; ++u) ac[u] = (f32x4){0.f,0.f,0.f,0.f};
      #pragma unroll
      for (int kk = 0; kk < 4; ++kk) {
        #pragma unroll
        for (int u = 0; u < 4; ++u)
          ac[u] = __builtin_amdgcn_mfma_f32_16x16x32_bf16(t2f[u][kk], wfr[kk], ac[u], 0, 0, 0);
      }
      float* cp = (float*)A1c;   // coup[sc][b][n], row stride 132 (padded, bank-friendly)
      if (b16 < 8) {
        #pragma unroll
        for (int u = 0; u < 4; ++u) {
          const int c  = (wave + 4*u)*16 + q*4;
          const int sc2 = c >> 7, nl = c & 127;
          #pragma unroll
          for (int r = 0; r < 4; ++r)
            cp[sc2*1056 + b16*132 + nl + r] = ac[u][r];
        }
      }
    }
    __syncthreads();

    // ---- Phase E: combine + RK4 update (fp32)
    {
      const int b = tid >> 5, nb = (tid & 31) << 2;
      const float* cp = (const float*)A1c;
      f32x4 wc = *(const f32x4*)(cp + b*132 + nb);
      f32x4 wsv = *(const f32x4*)(cp + 1056 + b*132 + nb);
      f32x4 cf = *(const f32x4*)(csf + b*128 + nb);
      f32x4 sf = *(const f32x4*)(csf + 1024 + b*128 + nb);
      const float swt = tc.s[e], cwt = tc.c[e];
      f32x4 kv;
      #pragma unroll
      for (int u = 0; u < 4; ++u)
        kv[u] = (sf[u]*wc[u] - cf[u]*wsv[u])              // K_COUP = 1
              + 0.08f*(swt*cf[u] - cwt*sf[u]);            // A*sin(wt - phi)
      f32x4 ph0 = *(const f32x4*)(phi0s + b*128 + nb);
      const int st = e & 3;
      f32x4 ka, pw;
      if (st == 0)      { ka = kv;                                              pw = ph0 + kv*half; }
      else if (st == 1) { ka = *(const f32x4*)(kaccs + b*128 + nb) + kv*2.0f;   pw = ph0 + kv*half; }
      else if (st == 2) { ka = *(const f32x4*)(kaccs + b*128 + nb) + kv*2.0f;   pw = ph0 + kv*dtf; }
      else {
        ka = *(const f32x4*)(kaccs + b*128 + nb) + kv;
        f32x4 pn = ph0 + ka*sixth;
        pw = pn;
        *(f32x4*)(phi0s + b*128 + nb) = pn;
      }
      *(f32x4*)(kaccs + b*128 + nb) = ka;
      *(f32x4*)(pws   + b*128 + nb) = pw;
    }
    __syncthreads();
  }

  // ---- epilogue: readout  out = [cos phiT, sin phiT] @ W_out^T + b_out
  {
    const int b = tid >> 5, nb = (tid & 31) << 2;
    f32x4 ph = *(const f32x4*)(phi0s + b*128 + nb);
    float part[10];
    #pragma unroll
    for (int cl = 0; cl < 10; ++cl) part[cl] = 0.0f;
    #pragma unroll
    for (int u = 0; u < 4; ++u) {
      float ss, cc; sincosf(ph[u], &ss, &cc);
      const int ng = jn0 + nb + u;
      #pragma unroll
      for (int cl = 0; cl < 10; ++cl)
        part[cl] += cc * W_out[cl*2048 + ng] + ss * W_out[cl*2048 + 1024 + ng];
    }
    #pragma unroll
    for (int off = 16; off >= 1; off >>= 1) {
      #pragma unroll
      for (int cl = 0; cl < 10; ++cl)
        part[cl] += __shfl_xor(part[cl], off, 32);
    }
    if ((tid & 31) == 0) {
      const int row = g*8 + b;
      #pragma unroll
      for (int cl = 0; cl < 10; ++cl) {
        float v = part[cl];
        if (j == 0) v += b_out[cl];
        atomicAdd(dout + row*10 + cl, v);
      }
    }
  }
}

extern "C" void kernel_launch(void* const* d_in, const int* in_sizes, int n_in,
                              void* d_out, int out_size, void* d_ws, size_t ws_size,
                              hipStream_t stream) {
  (void)in_sizes; (void)n_in; (void)ws_size;
  const float* x     = (const float*)d_in[0];
  const float* W_enc = (const float*)d_in[1];
  const float* b_enc = (const float*)d_in[2];
  const float* xi    = (const float*)d_in[3];
  const float* W_out = (const float*)d_in[4];
  const float* b_out = (const float*)d_in[5];
  float* out = (float*)d_out;

  char* wsb = (char*)d_ws;                             // [0,1 MiB) mpart, [1,1.25 MiB) wub
  unsigned int* ctrl = (unsigned int*)(wsb + (2 << 20)); // 16 KiB flag slots (A/B interleaved)

  hipMemsetAsync(d_out, 0, (size_t)out_size * sizeof(float), stream);
  hipMemsetAsync(ctrl, 0, 16*1024, stream);

  TCons tc;
  const double OME = 2.0 * 3.14159265358979323846 * 200.0;
  const double dtd = 0.03125;
  const double co[4] = {0.0, 0.5, 0.5, 1.0};
  for (int e = 0; e < 64; ++e) {
    double t = ((double)(e >> 2) + co[e & 3]) * dtd;
    tc.s[e] = (float)sin(OME * t);
    tc.c[e] = (float)cos(OME * t);
  }

  phasenn_kernel<<<dim3(256), dim3(256), 0, stream>>>(
      x, W_enc, b_enc, xi, W_out, b_out, out, wsb, ctrl, tc);
}